// Round 8
// baseline (2549.834 us; speedup 1.0000x reference)
//
#include <hip/hip_runtime.h>
#include <math.h>

// FAENet forward. All GEMMs via bf16 MFMA (16x16x32), fp32 accumulate.
// edge_embed_fused: [rp|ea]->LDS->MFMA(K=64)->silu->LDS(rot)->MFMA(K=128)->silu
//   ->LDS->full-row uint4 permuted store (fixes partial-line write amplification).
// msg_fused (per layer): MFMA el-tile -> LDS bf16 -> per-wave run-accumulated
//   gather over dst-sorted edges -> atomicAdd agg at run boundaries only.
// out_reduce: contiguous per-wave chunks over sorted batch (~2K atomics).

#define EPS_GN 1e-5f

typedef __attribute__((ext_vector_type(8))) short bf16x8;
typedef __attribute__((ext_vector_type(4))) float f32x4;

__device__ __forceinline__ float silu_f(float x) {
    return x / (1.0f + __expf(-x));
}
__device__ __forceinline__ float bf2f(unsigned int u) {
    union { unsigned int i; float f; } c;
    c.i = u << 16;
    return c.f;
}
__device__ __forceinline__ unsigned int f2bf(float x) {
    union { float f; unsigned int i; } c;
    c.f = x;
    unsigned int r = c.i + 0x7fffu + ((c.i >> 16) & 1u);
    return r >> 16;
}

enum { A_BF16 = 0, A_F32 = 1 };
enum { ME_STORE_F32 = 0, ME_STORE_BF16 = 1, ME_RESID = 3 };

// C[M x NFTOT] = epi(A[M x K] @ W[NFTOT x K]^T + bias), MFMA bf16.
template<int K, int AMODE, int EPI, bool PRELW>
__global__ __launch_bounds__(256)
void mgemm(const void* __restrict__ Ap, const unsigned short* __restrict__ Wp,
           const float* __restrict__ bias, float* __restrict__ Cf,
           unsigned short* __restrict__ Cb, int M, int NFTOT)
{
    constexpr int KS = K / 32;
    const int tid = threadIdx.x;
    const int lane = tid & 63;
    const int wv = tid >> 6;                    // 0..3
    const int l16 = lane & 15;
    const int quad = lane >> 4;                 // 0..3
    const int m0 = blockIdx.x * 128 + (wv >> 1) * 64;
    const int n0 = blockIdx.y * 128 + (wv & 1) * 64;

    bf16x8 wpre[PRELW ? (KS * 4) : 1];
    if (PRELW) {
#pragma unroll
        for (int t = 0; t < 4; ++t)
#pragma unroll
            for (int s = 0; s < KS; ++s)
                wpre[t * KS + s] = *(const bf16x8*)(Wp +
                    (size_t)(n0 + 16 * t + l16) * K + s * 32 + quad * 8);
    }

    f32x4 acc[4][4];
#pragma unroll
    for (int i = 0; i < 4; ++i)
#pragma unroll
        for (int j = 0; j < 4; ++j) acc[i][j] = (f32x4){0.f, 0.f, 0.f, 0.f};

    for (int s = 0; s < KS; ++s) {
        bf16x8 af[4];
#pragma unroll
        for (int t = 0; t < 4; ++t) {
            int r = m0 + 16 * t + l16;
            if (r >= M) r = M - 1;
            if (AMODE == A_BF16) {
                af[t] = *(const bf16x8*)((const unsigned short*)Ap +
                                         (size_t)r * K + s * 32 + quad * 8);
            } else {
                const float* ap = (const float*)Ap + (size_t)r * K + s * 32 + quad * 8;
                float4 x0 = *(const float4*)ap;
                float4 x1 = *(const float4*)(ap + 4);
                bf16x8 v;
                v[0] = (short)f2bf(x0.x); v[1] = (short)f2bf(x0.y);
                v[2] = (short)f2bf(x0.z); v[3] = (short)f2bf(x0.w);
                v[4] = (short)f2bf(x1.x); v[5] = (short)f2bf(x1.y);
                v[6] = (short)f2bf(x1.z); v[7] = (short)f2bf(x1.w);
                af[t] = v;
            }
        }
        bf16x8 wf[4];
#pragma unroll
        for (int t = 0; t < 4; ++t) {
            if (PRELW) wf[t] = wpre[t * KS + s];
            else       wf[t] = *(const bf16x8*)(Wp +
                           (size_t)(n0 + 16 * t + l16) * K + s * 32 + quad * 8);
        }
#pragma unroll
        for (int tm = 0; tm < 4; ++tm)
#pragma unroll
            for (int tn = 0; tn < 4; ++tn)
                acc[tm][tn] = __builtin_amdgcn_mfma_f32_16x16x32_bf16(
                    af[tm], wf[tn], acc[tm][tn], 0, 0, 0);
    }

#pragma unroll
    for (int tn = 0; tn < 4; ++tn) {
        int c = n0 + 16 * tn + l16;
        float bv = bias[c];
#pragma unroll
        for (int tm = 0; tm < 4; ++tm) {
            int rb = m0 + 16 * tm + quad * 4;
#pragma unroll
            for (int rg = 0; rg < 4; ++rg) {
                int r = rb + rg;
                if (r >= M) continue;
                float v = silu_f(acc[tm][tn][rg] + bv);
                if (EPI == ME_STORE_F32) {
                    Cf[(size_t)r * NFTOT + c] = v;
                } else if (EPI == ME_STORE_BF16) {
                    Cb[(size_t)r * NFTOT + c] = (unsigned short)f2bf(v);
                } else { // ME_RESID
                    Cf[(size_t)r * NFTOT + c] += v;
                }
            }
        }
    }
}

// Fused message+gather: el = silu(e@W^T+b) (MFMA, tile->LDS bf16), then each
// wave walks 32 dst-sorted edges: agg[dst] += el[p] * hd[src[p]], run-combined.
__global__ __launch_bounds__(256)
void msg_fused(const unsigned short* __restrict__ ebf,
               const unsigned short* __restrict__ Wp,
               const float* __restrict__ bias,
               const unsigned int* __restrict__ hd2,   // N x 64 uints (bf16x2)
               const int* __restrict__ src_s, const int* __restrict__ dst_s,
               float* __restrict__ agg, int E)
{
    __shared__ unsigned short sE[128 * 132];
    const int tid = threadIdx.x;
    const int lane = tid & 63;
    const int wv = tid >> 6;
    const int l16 = lane & 15;
    const int quad = lane >> 4;
    const int m0 = blockIdx.x * 128;
    const int mw = (wv >> 1) * 64;
    const int nw = (wv & 1) * 64;

    // W preload: 16 frags (K=128)
    bf16x8 wpre[16];
#pragma unroll
    for (int t = 0; t < 4; ++t)
#pragma unroll
        for (int s = 0; s < 4; ++s)
            wpre[t * 4 + s] = *(const bf16x8*)(Wp +
                (size_t)(nw + 16 * t + l16) * 128 + s * 32 + quad * 8);

    f32x4 acc[4][4];
#pragma unroll
    for (int i = 0; i < 4; ++i)
#pragma unroll
        for (int j = 0; j < 4; ++j) acc[i][j] = (f32x4){0.f, 0.f, 0.f, 0.f};

#pragma unroll
    for (int s = 0; s < 4; ++s) {
        bf16x8 af[4];
#pragma unroll
        for (int t = 0; t < 4; ++t) {
            int r = m0 + mw + 16 * t + l16;
            if (r >= E) r = E - 1;
            af[t] = *(const bf16x8*)(ebf + (size_t)r * 128 + s * 32 + quad * 8);
        }
#pragma unroll
        for (int tm = 0; tm < 4; ++tm)
#pragma unroll
            for (int tn = 0; tn < 4; ++tn)
                acc[tm][tn] = __builtin_amdgcn_mfma_f32_16x16x32_bf16(
                    af[tm], wpre[tn * 4 + s], acc[tm][tn], 0, 0, 0);
    }

    // silu+bias -> sE (bf16, stride 132)
#pragma unroll
    for (int tn = 0; tn < 4; ++tn) {
        int c = nw + 16 * tn + l16;
        float bv = bias[c];
#pragma unroll
        for (int tm = 0; tm < 4; ++tm) {
            int rl = mw + 16 * tm + quad * 4;
#pragma unroll
            for (int rg = 0; rg < 4; ++rg)
                sE[(rl + rg) * 132 + c] =
                    (unsigned short)f2bf(silu_f(acc[tm][tn][rg] + bv));
        }
    }
    __syncthreads();

    // gather phase: wave wv handles edges [m0+wv*32, m0+wv*32+32)
    int p0 = m0 + wv * 32;
    int pend = p0 + 32; if (pend > E) pend = E;
    if (p0 >= E) return;
    int cur = dst_s[p0];
    float a0 = 0.f, a1 = 0.f;
    for (int p = p0; p < pend; ++p) {
        int d = dst_s[p];
        if (d != cur) {
            float* arow = agg + (size_t)cur * 128 + 2 * lane;
            atomicAdd(arow, a0);
            atomicAdd(arow + 1, a1);
            cur = d; a0 = 0.f; a1 = 0.f;
        }
        unsigned int e2 = *(const unsigned int*)(sE + (p - m0) * 132 + 2 * lane);
        unsigned int h2 = hd2[(size_t)src_s[p] * 64 + lane];
        a0 = fmaf(bf2f(e2 & 0xffffu), bf2f(h2 & 0xffffu), a0);
        a1 = fmaf(bf2f(e2 >> 16),     bf2f(h2 >> 16),     a1);
    }
    float* arow = agg + (size_t)cur * 128 + 2 * lane;
    atomicAdd(arow, a0);
    atomicAdd(arow + 1, a1);
}

// Wcat[128 x 64] bf16 matching sA layout [rp k=0..2 | ea k=3..52 | pad].
__global__ __launch_bounds__(256)
void build_wcat(const float* __restrict__ w1, const float* __restrict__ w12,
                const float* __restrict__ b1, const float* __restrict__ b12,
                unsigned short* __restrict__ wcat, float* __restrict__ bcat)
{
    int i = blockIdx.x * 256 + threadIdx.x;
    if (i < 8192) {
        int r = i >> 6, c = i & 63;
        float v = 0.f;
        if (r < 64) { if (c < 3) v = w1[r * 3 + c]; }
        else        { if (c >= 3 && c < 53) v = w12[(r - 64) * 50 + (c - 3)]; }
        wcat[i] = (unsigned short)f2bf(v);
    }
    if (i < 128) bcat[i] = (i < 64) ? b1[i] : b12[i - 64];
}

// Fused edge embedding: e[perm[r]] = silu(silu([rp|ea]@Wcat^T+bcat)@W2^T+b2)
__global__ __launch_bounds__(256)
void edge_embed_fused(const float* __restrict__ rp, const float* __restrict__ ea,
                      const unsigned short* __restrict__ wcat,
                      const float* __restrict__ bcat,
                      const unsigned short* __restrict__ w2,
                      const float* __restrict__ b2,
                      const int* __restrict__ perm,
                      unsigned short* __restrict__ ebf, int E)
{
    __shared__ unsigned short sA[128 * 72];   // [row][k0..63], stride 72
    __shared__ unsigned short sT[128 * 128];  // t-tile (rot-swizzled) / out-tile
    const int tid = threadIdx.x;
    const int m0 = blockIdx.x * 128;

    // stage [rp|ea] -> sA (bf16): rp at k=0..2, ea at k=3..52, zero-pad 53..63
    for (int i = tid; i < 128 * 11; i += 256) {
        int r = i / 11, c = i - r * 11;
        sA[r * 72 + 53 + c] = 0;
    }
    for (int i = tid; i < 384; i += 256) {
        int r = i / 3, c = i - r * 3;
        sA[r * 72 + c] = (unsigned short)f2bf(rp[(size_t)m0 * 3 + i]);
    }
    for (int i = tid; i < 6400; i += 256) {
        int r = i / 50, c = i - r * 50;
        sA[r * 72 + 3 + c] = (unsigned short)f2bf(ea[(size_t)m0 * 50 + i]);
    }
    __syncthreads();

    const int lane = tid & 63;
    const int wv = tid >> 6;
    const int l16 = lane & 15, quad = lane >> 4;
    const int mw = (wv >> 1) * 64;
    const int nw = (wv & 1) * 64;

    // stage 1: t = silu(A @ Wcat^T + bcat), K=64
    f32x4 acc[4][4];
#pragma unroll
    for (int i = 0; i < 4; ++i)
#pragma unroll
        for (int j = 0; j < 4; ++j) acc[i][j] = (f32x4){0.f, 0.f, 0.f, 0.f};
#pragma unroll
    for (int s = 0; s < 2; ++s) {
        bf16x8 af[4], wf[4];
#pragma unroll
        for (int t = 0; t < 4; ++t)
            af[t] = *(const bf16x8*)(sA + (mw + 16 * t + l16) * 72 + s * 32 + quad * 8);
#pragma unroll
        for (int t = 0; t < 4; ++t)
            wf[t] = *(const bf16x8*)(wcat +
                (size_t)(nw + 16 * t + l16) * 64 + s * 32 + quad * 8);
#pragma unroll
        for (int tm = 0; tm < 4; ++tm)
#pragma unroll
            for (int tn = 0; tn < 4; ++tn)
                acc[tm][tn] = __builtin_amdgcn_mfma_f32_16x16x32_bf16(
                    af[tm], wf[tn], acc[tm][tn], 0, 0, 0);
    }
    // silu+bias -> sT with k-group rotation swizzle: group g stored at (g+r)&15
#pragma unroll
    for (int tn = 0; tn < 4; ++tn) {
        int c = nw + 16 * tn + l16;
        float bv = bcat[c];
#pragma unroll
        for (int tm = 0; tm < 4; ++tm) {
            int rb = mw + 16 * tm + quad * 4;
#pragma unroll
            for (int rg = 0; rg < 4; ++rg) {
                int r = rb + rg;
                int g = ((c >> 3) + r) & 15;
                sT[r * 128 + g * 8 + (c & 7)] =
                    (unsigned short)f2bf(silu_f(acc[tm][tn][rg] + bv));
            }
        }
    }
    __syncthreads();

    // stage 2: e = silu(t @ W2^T + b2), K=128
    f32x4 acc2[4][4];
#pragma unroll
    for (int i = 0; i < 4; ++i)
#pragma unroll
        for (int j = 0; j < 4; ++j) acc2[i][j] = (f32x4){0.f, 0.f, 0.f, 0.f};
#pragma unroll
    for (int s = 0; s < 4; ++s) {
        bf16x8 af[4], wf[4];
#pragma unroll
        for (int t = 0; t < 4; ++t) {
            int r = mw + 16 * t + l16;
            int g = (s * 4 + quad + r) & 15;
            af[t] = *(const bf16x8*)(sT + r * 128 + g * 8);
        }
#pragma unroll
        for (int t = 0; t < 4; ++t)
            wf[t] = *(const bf16x8*)(w2 +
                (size_t)(nw + 16 * t + l16) * 128 + s * 32 + quad * 8);
#pragma unroll
        for (int tm = 0; tm < 4; ++tm)
#pragma unroll
            for (int tn = 0; tn < 4; ++tn)
                acc2[tm][tn] = __builtin_amdgcn_mfma_f32_16x16x32_bf16(
                    af[tm], wf[tn], acc2[tm][tn], 0, 0, 0);
    }
    __syncthreads();  // all stage-2 reads of sT done before overwrite

    // out-tile -> sT (linear layout)
#pragma unroll
    for (int tn = 0; tn < 4; ++tn) {
        int c = nw + 16 * tn + l16;
        float bv = b2[c];
#pragma unroll
        for (int tm = 0; tm < 4; ++tm) {
            int rb = mw + 16 * tm + quad * 4;
#pragma unroll
            for (int rg = 0; rg < 4; ++rg)
                sT[(rb + rg) * 128 + c] =
                    (unsigned short)f2bf(silu_f(acc2[tm][tn][rg] + bv));
        }
    }
    __syncthreads();

    // full-row permuted copy-out: 16 threads/row write uint4 (8 shorts) each
    for (int pass = 0; pass < 8; ++pass) {
        int idx = pass * 256 + tid;
        int row = idx >> 4, chunk = idx & 15;
        int gr = m0 + row;
        if (gr < E) {
            int pr = perm[gr];
            *(uint4*)(ebf + (size_t)pr * 128 + chunk * 8) =
                *(const uint4*)(sT + row * 128 + chunk * 8);
        }
    }
}

// hb0[n][0:224]=emb_w[z[n]], [224:256]=tag_emb_w[tag[n]]  (f32)
__global__ __launch_bounds__(256)
void node_gather(const int* __restrict__ z, const int* __restrict__ tag,
                 const float* __restrict__ embw, const float* __restrict__ tembw,
                 float* __restrict__ hb0, int N)
{
    int lane = threadIdx.x & 63;
    int n = blockIdx.x * 4 + (threadIdx.x >> 6);
    if (n >= N) return;
    int f = lane * 4;
    float4 v;
    if (f < 224) v = *(const float4*)(embw + (size_t)z[n] * 224 + f);
    else         v = *(const float4*)(tembw + (size_t)tag[n] * 32 + (f - 224));
    *(float4*)(hb0 + (size_t)n * 256 + f) = v;
}

__global__ __launch_bounds__(256)
void cvt_bf16(const float* __restrict__ src, unsigned short* __restrict__ dst, int n)
{
    int i = blockIdx.x * 256 + threadIdx.x;
    if (i < n) dst[i] = (unsigned short)f2bf(src[i]);
}

// ---- counting sort by dst ----
__global__ __launch_bounds__(256)
void edge_hist(const int* __restrict__ dst, int* __restrict__ cnt, int E)
{
    for (int i = blockIdx.x * 256 + threadIdx.x; i < E; i += gridDim.x * 256)
        atomicAdd(&cnt[dst[i]], 1);
}

__global__ __launch_bounds__(1024)
void scan_excl(int* __restrict__ cnt, int N)
{
    __shared__ int sdata[1024];
    __shared__ int s_carry;
    int tid = threadIdx.x;
    if (tid == 0) s_carry = 0;
    __syncthreads();
    for (int base = 0; base < N; base += 1024) {
        int i = base + tid;
        int v = (i < N) ? cnt[i] : 0;
        sdata[tid] = v;
        __syncthreads();
        for (int off = 1; off < 1024; off <<= 1) {
            int t = (tid >= off) ? sdata[tid - off] : 0;
            __syncthreads();
            sdata[tid] += t;
            __syncthreads();
        }
        int excl = sdata[tid] - v + s_carry;
        if (i < N) cnt[i] = excl;
        int tot = sdata[1023];
        __syncthreads();
        if (tid == 0) s_carry += tot;
        __syncthreads();
    }
}

__global__ __launch_bounds__(256)
void edge_rank(const int* __restrict__ src, const int* __restrict__ dst,
               int* __restrict__ cursor, int* __restrict__ rank,
               int* __restrict__ src_s, int* __restrict__ dst_s, int E)
{
    for (int i = blockIdx.x * 256 + threadIdx.x; i < E; i += gridDim.x * 256) {
        int d = dst[i];
        int p = atomicAdd(&cursor[d], 1);
        rank[i] = p;
        src_s[p] = src[i];
        dst_s[p] = d;
    }
}

__global__ __launch_bounds__(256)
void gn_stats(const float* __restrict__ agg, float* __restrict__ sums, int N)
{
    __shared__ float red[512];
    int f = threadIdx.x & 127;
    int sub = threadIdx.x >> 7;
    float s = 0.f, s2 = 0.f;
    for (int r = blockIdx.x * 2 + sub; r < N; r += gridDim.x * 2) {
        float v = agg[(size_t)r * 128 + f];
        s += v;
        s2 += v * v;
    }
    red[threadIdx.x] = s;
    red[256 + threadIdx.x] = s2;
    __syncthreads();
    if (sub == 0) {
        s = red[f] + red[128 + f];
        s2 = red[256 + f] + red[384 + f];
        atomicAdd(&sums[f], s);
        atomicAdd(&sums[128 + f], s2);
    }
}

__global__ void gn_finalize(const float* __restrict__ sums,
                            const float* __restrict__ gnw, const float* __restrict__ gnb,
                            const float* __restrict__ gnms, float* __restrict__ ab,
                            float invN)
{
    int f = threadIdx.x; // 128
    float mean = sums[f] * invN;
    float ex2 = sums[128 + f] * invN;
    float m2 = mean * gnms[f];
    float var = ex2 - 2.f * m2 * mean + m2 * m2;
    float rstd = 1.0f / sqrtf(var + EPS_GN);
    float a = gnw[f] * rstd;
    ab[f] = a;
    ab[128 + f] = gnb[f] - a * m2;
}

// ga = bf16(silu(a*agg+b)) elementwise
__global__ __launch_bounds__(256)
void gn_apply(const float* __restrict__ agg, const float* __restrict__ ab,
              unsigned int* __restrict__ ga, int n2 /* N*64 */)
{
    for (int i = blockIdx.x * 256 + threadIdx.x; i < n2; i += gridDim.x * 256) {
        int f = (i & 63) * 2;
        float2 v = *(const float2*)(agg + (size_t)i * 2);
        float r0 = silu_f(ab[f] * v.x + ab[128 + f]);
        float r1 = silu_f(ab[f + 1] * v.y + ab[129 + f]);
        ga[i] = f2bf(r0) | (f2bf(r1) << 16);
    }
}

// out[g] += per-graph sum of (h1[r].w2)+b2 over sorted batch, run-accumulated.
__global__ __launch_bounds__(256)
void out_reduce(const float* __restrict__ h1, const float* __restrict__ w2,
                const float* __restrict__ b2, const int* __restrict__ batch,
                float* __restrict__ out, int N)
{
    int lane = threadIdx.x & 63;
    int wid = blockIdx.x * 4 + (threadIdx.x >> 6);
    int nwaves = gridDim.x * 4;
    int chunk = (N + nwaves - 1) / nwaves;
    int r0 = wid * chunk;
    int r1 = r0 + chunk; if (r1 > N) r1 = N;
    if (r0 >= r1) return;
    float wa = w2[lane], wb = w2[64 + lane];
    float bb = b2[0];
    int cur = batch[r0];
    float acc = 0.f;
    int cnt = 0;
    for (int r = r0; r < r1; ++r) {
        int g = batch[r];
        if (g != cur) {
            float v = acc;
#pragma unroll
            for (int o = 32; o > 0; o >>= 1) v += __shfl_down(v, o);
            if (lane == 0) atomicAdd(&out[cur], v + (float)cnt * bb);
            cur = g; acc = 0.f; cnt = 0;
        }
        acc = fmaf(h1[(size_t)r * 128 + lane], wa, acc);
        acc = fmaf(h1[(size_t)r * 128 + 64 + lane], wb, acc);
        ++cnt;
    }
    float v = acc;
#pragma unroll
    for (int o = 32; o > 0; o >>= 1) v += __shfl_down(v, o);
    if (lane == 0) atomicAdd(&out[cur], v + (float)cnt * bb);
}

extern "C" void kernel_launch(void* const* d_in, const int* in_sizes, int n_in,
                              void* d_out, int out_size, void* d_ws, size_t ws_size,
                              hipStream_t stream)
{
    const int*   z         = (const int*)d_in[0];
    const int*   tag       = (const int*)d_in[1];
    const float* rel_pos   = (const float*)d_in[2];
    const float* edge_attr = (const float*)d_in[3];
    const int*   eidx      = (const int*)d_in[4];
    const int*   batch     = (const int*)d_in[5];
    const float* le1w  = (const float*)d_in[6];
    const float* le1b  = (const float*)d_in[7];
    const float* le12w = (const float*)d_in[8];
    const float* le12b = (const float*)d_in[9];
    const float* le2w  = (const float*)d_in[10];
    const float* le2b  = (const float*)d_in[11];
    const float* embw  = (const float*)d_in[12];
    const float* tembw = (const float*)d_in[13];
    const float* linw  = (const float*)d_in[14];
    const float* linb  = (const float*)d_in[15];
    const float* lin2w = (const float*)d_in[16];
    const float* lin2b = (const float*)d_in[17];
    const float* geomw = (const float*)d_in[18];
    const float* geomb = (const float*)d_in[19];
    const float* downw = (const float*)d_in[20];
    const float* downb = (const float*)d_in[21];
    const float* upw   = (const float*)d_in[22];
    const float* upb   = (const float*)d_in[23];
    const float* gnw   = (const float*)d_in[24];
    const float* gnb   = (const float*)d_in[25];
    const float* gnms  = (const float*)d_in[26];
    const float* o1w   = (const float*)d_in[27];
    const float* o1b   = (const float*)d_in[28];
    const float* o2w   = (const float*)d_in[29];
    const float* o2b   = (const float*)d_in[30];

    const int N = in_sizes[0];
    const int E = in_sizes[2] / 3;
    const int* esrc = eidx;
    const int* edst = eidx + E;

    char* ws = (char*)d_ws;
    size_t off = 0;
    unsigned short* T = (unsigned short*)(ws + off); off += (size_t)E * 128 * 2;   // hb0+t1
    unsigned short* ebf = (unsigned short*)(ws + off); off += (size_t)E * 128 * 2;
    float* h   = (float*)(ws + off); off += (size_t)N * 256 * 4;
    float* agg = (float*)(ws + off); off += (size_t)N * 128 * 4;
    unsigned short* hdb = (unsigned short*)(ws + off); off += (size_t)N * 128 * 2;
    int*   cnt   = (int*)(ws + off); off += (size_t)N * 4;
    int*   src_s = (int*)(ws + off); off += (size_t)E * 4;
    int*   dst_s = (int*)(ws + off); off += (size_t)E * 4;
    unsigned short* wbuf = (unsigned short*)(ws + off); off += 442368ull * 2;
    float* stats = (float*)(ws + off); off += 256 * 4;
    float* ab    = (float*)(ws + off); off += 256 * 4;
    float* bcat  = (float*)(ws + off); off += 128;

    // aliases
    float* hb0 = (float*)T;                         // N*256 f32
    float* t1  = (float*)T + (size_t)N * 256;       // N*256 f32 (dead before layers)
    int*   rank = (int*)agg;                        // E ints, dead before agg first write
    unsigned short* ga = hdb;                       // bf16 N*128, written after msg_fused
    float* h1 = agg;                                // N*128 f32, written after agg last read

    // bf16 weight buffer offsets
    unsigned short* wb_le2  = wbuf;                 // 16384
    unsigned short* wb_geom = wbuf + 16384;         // 3*16384
    unsigned short* wb_down = wbuf + 65536;         // 3*32768
    unsigned short* wb_up   = wbuf + 163840;        // 3*32768
    unsigned short* wb_lin  = wbuf + 262144;        // 65536
    unsigned short* wb_lin2 = wbuf + 327680;        // 65536
    unsigned short* wb_o1   = wbuf + 393216;        // 32768
    unsigned short* wb_cat  = wbuf + 425984;        // 8192

    const int mbE = (E + 127) / 128;
    const int mbN = (N + 127) / 128;
    dim3 blk(256);

    // weight conversions
    cvt_bf16<<<dim3(64), blk, 0, stream>>>(le2w, wb_le2, 16384);
    cvt_bf16<<<dim3(192), blk, 0, stream>>>(geomw, wb_geom, 49152);
    cvt_bf16<<<dim3(384), blk, 0, stream>>>(downw, wb_down, 98304);
    cvt_bf16<<<dim3(384), blk, 0, stream>>>(upw, wb_up, 98304);
    cvt_bf16<<<dim3(256), blk, 0, stream>>>(linw, wb_lin, 65536);
    cvt_bf16<<<dim3(256), blk, 0, stream>>>(lin2w, wb_lin2, 65536);
    cvt_bf16<<<dim3(128), blk, 0, stream>>>(o1w, wb_o1, 32768);
    build_wcat<<<dim3(32), blk, 0, stream>>>(le1w, le12w, le1b, le12b, wb_cat, bcat);

    // counting sort by dst
    hipMemsetAsync(cnt, 0, (size_t)N * sizeof(int), stream);
    edge_hist<<<dim3(3125), blk, 0, stream>>>(edst, cnt, E);
    scan_excl<<<dim3(1), dim3(1024), 0, stream>>>(cnt, N);
    edge_rank<<<dim3(3125), blk, 0, stream>>>(esrc, edst, cnt, rank, src_s, dst_s, E);

    // fused edge embedding (permuted into dst-sorted order)
    edge_embed_fused<<<dim3(mbE), blk, 0, stream>>>(
        rel_pos, edge_attr, wb_cat, bcat, wb_le2, le2b, rank, ebf, E);

    // node embedding: hb0 -> t1 -> h
    node_gather<<<dim3((N + 3) / 4), blk, 0, stream>>>(z, tag, embw, tembw, hb0, N);
    mgemm<256, A_F32, ME_STORE_F32, false><<<dim3(mbN, 2), blk, 0, stream>>>(
        hb0, wb_lin, linb, t1, nullptr, N, 256);
    mgemm<256, A_F32, ME_STORE_F32, false><<<dim3(mbN, 2), blk, 0, stream>>>(
        t1, wb_lin2, lin2b, h, nullptr, N, 256);

    // interaction blocks
    for (int l = 0; l < 3; ++l) {
        mgemm<256, A_F32, ME_STORE_BF16, false><<<dim3(mbN, 1), blk, 0, stream>>>(
            h, wb_down + (size_t)l * 32768, downb + (size_t)l * 128,
            nullptr, hdb, N, 128);
        hipMemsetAsync(agg, 0, (size_t)N * 128 * sizeof(float), stream);
        msg_fused<<<dim3(mbE), blk, 0, stream>>>(
            ebf, wb_geom + (size_t)l * 16384, geomb + (size_t)l * 128,
            (const unsigned int*)hdb, src_s, dst_s, agg, E);
        hipMemsetAsync(stats, 0, 256 * sizeof(float), stream);
        gn_stats<<<dim3(256), blk, 0, stream>>>(agg, stats, N);
        gn_finalize<<<dim3(1), dim3(128), 0, stream>>>(
            stats, gnw + (size_t)l * 128, gnb + (size_t)l * 128,
            gnms + (size_t)l * 128, ab, 1.0f / (float)N);
        gn_apply<<<dim3(512), blk, 0, stream>>>(agg, ab, (unsigned int*)ga, N * 64);
        mgemm<128, A_BF16, ME_RESID, true><<<dim3(mbN, 2), blk, 0, stream>>>(
            ga, wb_up + (size_t)l * 32768, upb + (size_t)l * 256,
            h, nullptr, N, 256);
    }

    // readout
    mgemm<256, A_F32, ME_STORE_F32, false><<<dim3(mbN, 1), blk, 0, stream>>>(
        h, wb_o1, o1b, h1, nullptr, N, 128);
    hipMemsetAsync(d_out, 0, 32 * sizeof(float), stream);
    out_reduce<<<dim3(512), blk, 0, stream>>>(h1, o2w, o2b, batch, (float*)d_out, N);
}